// Round 11
// baseline (341.525 us; speedup 1.0000x reference)
//
#include <hip/hip_runtime.h>

#define N_NODES  100000
#define M_PAD    100096   // 782 * 128
#define N_EDGES  1600000
#define N_GRAPHS 512
#define IN_DIM   128
#define HID_DIM  256
#define OUT_DIM  128

#define NB       782      // buckets of 128 nodes
#define BCAP     3072     // mean 2048, +22 sigma headroom
#define CHUNK    2048     // edges per bucket_v2 block
#define BKB      ((N_EDGES + CHUNK - 1) / CHUNK)   // 782

typedef __bf16 bf16x8 __attribute__((ext_vector_type(8)));
typedef __bf16 bf16x4 __attribute__((ext_vector_type(4)));
typedef __bf16 bf16x2 __attribute__((ext_vector_type(2)));
typedef float  f32x4  __attribute__((ext_vector_type(4)));

// ---- packed weight buffer layout (frag-ordered; see init decode) ----
#define WP_L2_BASE 32768
#define WP_L3_BASE 98304
#define WP_TOTAL   131072

// ---------------- fused init ----------------
#define R_X    (N_NODES * IN_DIM / 4)
#define R_APAD ((M_PAD - N_NODES) * IN_DIM / 4)
#define R_WP   WP_TOTAL
#define R_OUT  (N_GRAPHS * OUT_DIM / 4)
#define R_CUR  NB
#define R_TOTAL (R_X + R_APAD + R_WP + R_OUT + R_CUR)

__global__ __launch_bounds__(256) void init_kernel(const float* __restrict__ x,
                                                   const float* __restrict__ W1,
                                                   const float* __restrict__ W2,
                                                   const float* __restrict__ Wo,
                                                   __bf16* __restrict__ xb,
                                                   __bf16* __restrict__ Apad,
                                                   __bf16* __restrict__ Wp,
                                                   float* __restrict__ outbuf,
                                                   int* __restrict__ gcursor) {
    long long i = (long long)blockIdx.x * blockDim.x + threadIdx.x;
    if (i < R_X) {
        float4 v = ((const float4*)x)[i];
        bf16x4 h;
        h.x = (__bf16)v.x; h.y = (__bf16)v.y; h.z = (__bf16)v.z; h.w = (__bf16)v.w;
        ((bf16x4*)xb)[i] = h;
        return;
    }
    i -= R_X;
    if (i < R_APAD) {
        bf16x4 z; z.x = (__bf16)0.f; z.y = (__bf16)0.f; z.z = (__bf16)0.f; z.w = (__bf16)0.f;
        ((bf16x4*)Apad)[i] = z;
        return;
    }
    i -= R_APAD;
    if (i < R_WP) {
        int idx = (int)i;
        const float* src;
        int K, Nn, base;
        if (idx < WP_L2_BASE)      { src = W1; K = 128; Nn = 256; base = 0; }
        else if (idx < WP_L3_BASE) { src = W2; K = 256; Nn = 256; base = WP_L2_BASE; }
        else                       { src = Wo; K = 256; Nn = 128; base = WP_L3_BASE; }
        int r0 = idx - base;
        int slabElems = 32 * K;          // power of two
        int j = r0 / slabElems;
        int r = r0 % slabElems;
        int KS = K / 32;
        int p = r >> 9;
        int lane = (r >> 3) & 63;
        int e = r & 7;
        int s = p % KS, t = p / KS;
        int quad = lane >> 4, l16 = lane & 15;
        int n = j * 32 + t * 16 + l16;
        int k = s * 32 + quad * 8 + e;
        Wp[idx] = (__bf16)src[(size_t)k * Nn + n];
        return;
    }
    i -= R_WP;
    if (i < R_OUT) {
        ((float4*)outbuf)[i] = make_float4(0.f, 0.f, 0.f, 0.f);
        return;
    }
    i -= R_OUT;
    if (i < R_CUR) gcursor[i] = 0;
}

// ---------------- bucket_v2: LDS-staged edge binning ----------------
__global__ __launch_bounds__(256) void bucket_v2_kernel(const int* __restrict__ ei,
                                                        int* __restrict__ gcursor,
                                                        unsigned* __restrict__ pairBuf) {
    __shared__ int lcnt[NB];
    __shared__ int lbase[NB];
    const int tid = threadIdx.x;
    const int e0 = blockIdx.x * CHUNK;

    for (int b = tid; b < NB; b += 256) lcnt[b] = 0;
    __syncthreads();

    for (int i = tid; i < CHUNK; i += 256) {
        int e = e0 + i;
        if (e < N_EDGES) atomicAdd(&lcnt[ei[N_EDGES + e] >> 7], 1);
    }
    __syncthreads();

    for (int b = tid; b < NB; b += 256) {
        int c = lcnt[b];
        lbase[b] = c ? atomicAdd(&gcursor[b], c) : 0;
        lcnt[b] = 0;
    }
    __syncthreads();

    for (int i = tid; i < CHUNK; i += 256) {
        int e = e0 + i;
        if (e < N_EDGES) {
            int s = ei[e];
            int d = ei[N_EDGES + e];
            int b = d >> 7;
            int pos = lbase[b] + atomicAdd(&lcnt[b], 1);
            if (pos < BCAP)
                pairBuf[(size_t)b * BCAP + pos] = (unsigned)s | ((unsigned)(d & 127) << 17);
        }
    }
}

// ---------------- passB: per-bucket CSR build (bucket-strided) ----------------
__global__ __launch_bounds__(256) void passB_kernel(const unsigned* __restrict__ pairBuf,
                                                    const int* __restrict__ gcursor,
                                                    int* __restrict__ nbr,
                                                    int* __restrict__ offsets,
                                                    int* __restrict__ deg) {
    __shared__ int lcnt[128];
    __shared__ int loffs[128];
    __shared__ int lcur[128];
    const int b = blockIdx.x;
    const int tid = threadIdx.x;
    const int node0 = b << 7;
    const int cnt = min(gcursor[b], BCAP);
    const int base = b * BCAP;
    const unsigned* pb = pairBuf + (size_t)b * BCAP;

    if (tid < 128) { lcnt[tid] = 0; lcur[tid] = 0; }
    __syncthreads();

    for (int i = tid; i < cnt; i += 256)
        atomicAdd(&lcnt[pb[i] >> 17], 1);
    __syncthreads();

    if (tid < 128) loffs[tid] = lcnt[tid];
    __syncthreads();
    for (int st = 1; st < 128; st <<= 1) {
        int add = (tid < 128 && tid >= st) ? loffs[tid - st] : 0;
        __syncthreads();
        if (tid < 128) loffs[tid] += add;
        __syncthreads();
    }
    int excl = 0;
    if (tid < 128) {
        excl = loffs[tid] - lcnt[tid];
        int node = node0 + tid;
        if (node < N_NODES) {
            deg[node] = lcnt[tid];
            offsets[node] = base + excl;
        }
    }
    __syncthreads();
    if (tid < 128) loffs[tid] = excl;
    __syncthreads();

    for (int i = tid; i < cnt; i += 256) {
        unsigned u = pb[i];
        int dl = u >> 17;
        int slot = atomicAdd(&lcur[dl], 1);
        nbr[base + loffs[dl] + slot] = (int)(u & 0x1FFFF);
    }
}

// ---------------- gather aggregate (at memory floor) ----------------
__global__ __launch_bounds__(256) void aggregate_kernel(const __bf16* __restrict__ xb,
                                                        const int* __restrict__ offsets,
                                                        const int* __restrict__ deg,
                                                        const int* __restrict__ nbr,
                                                        __bf16* __restrict__ A) {
    int v = blockIdx.x * 4 + (threadIdx.x >> 6);
    v = __builtin_amdgcn_readfirstlane(v);
    int lane = threadIdx.x & 63;
    if (v >= N_NODES) return;
    int off = offsets[v];
    int len = deg[v];
    const int c0 = lane * 2;
    bf16x2 self = *(const bf16x2*)(xb + (size_t)v * IN_DIM + c0);
    float ax = (float)self.x, ay = (float)self.y;

    int addr = off + lane;
    if (addr > NB * BCAP - 1) addr = NB * BCAP - 1;
    int myidx = nbr[addr];

    int lim = len < 64 ? len : 64;
    int j = 0;
    for (; j + 8 <= lim; j += 8) {
        int s0 = __shfl(myidx, j + 0, 64);
        int s1 = __shfl(myidx, j + 1, 64);
        int s2 = __shfl(myidx, j + 2, 64);
        int s3 = __shfl(myidx, j + 3, 64);
        int s4 = __shfl(myidx, j + 4, 64);
        int s5 = __shfl(myidx, j + 5, 64);
        int s6 = __shfl(myidx, j + 6, 64);
        int s7 = __shfl(myidx, j + 7, 64);
        bf16x2 v0 = *(const bf16x2*)(xb + (size_t)s0 * IN_DIM + c0);
        bf16x2 v1 = *(const bf16x2*)(xb + (size_t)s1 * IN_DIM + c0);
        bf16x2 v2 = *(const bf16x2*)(xb + (size_t)s2 * IN_DIM + c0);
        bf16x2 v3 = *(const bf16x2*)(xb + (size_t)s3 * IN_DIM + c0);
        bf16x2 v4 = *(const bf16x2*)(xb + (size_t)s4 * IN_DIM + c0);
        bf16x2 v5 = *(const bf16x2*)(xb + (size_t)s5 * IN_DIM + c0);
        bf16x2 v6 = *(const bf16x2*)(xb + (size_t)s6 * IN_DIM + c0);
        bf16x2 v7 = *(const bf16x2*)(xb + (size_t)s7 * IN_DIM + c0);
        ax += (float)v0.x + (float)v1.x + (float)v2.x + (float)v3.x
            + (float)v4.x + (float)v5.x + (float)v6.x + (float)v7.x;
        ay += (float)v0.y + (float)v1.y + (float)v2.y + (float)v3.y
            + (float)v4.y + (float)v5.y + (float)v6.y + (float)v7.y;
    }
    for (; j < lim; ++j) {
        int s = __shfl(myidx, j, 64);
        bf16x2 vv = *(const bf16x2*)(xb + (size_t)s * IN_DIM + c0);
        ax += (float)vv.x;
        ay += (float)vv.y;
    }
    for (; j < len; ++j) {
        int s = nbr[off + j];
        bf16x2 vv = *(const bf16x2*)(xb + (size_t)s * IN_DIM + c0);
        ax += (float)vv.x;
        ay += (float)vv.y;
    }
    bf16x2 h;
    h.x = (__bf16)ax;
    h.y = (__bf16)ay;
    *(bf16x2*)(A + (size_t)v * IN_DIM + c0) = h;
}

// ---------------- fused 3-layer MLP + pool (barrier-free slab loops) ----------------
// B-fragments read directly from global Wp (L2-resident, frag-ordered ->
// coalesced 1KB bursts). No Ws LDS, no per-slab barriers: waves free-run;
// only 2 barriers (layer transitions, intra-wave LDS write->read visibility).
// H: 128x256 bf16, XOR chunk swizzle, each wave touches only its 32 rows.
__global__ __launch_bounds__(256) void mlp_fused(const __bf16* __restrict__ A,
                                                 const __bf16* __restrict__ Wp,
                                                 const float* __restrict__ b1,
                                                 const float* __restrict__ b2,
                                                 const float* __restrict__ bo,
                                                 float* __restrict__ out,
                                                 const int* __restrict__ batch) {
    __shared__ __bf16 H[128 * 256];   // 64 KB

    const int tid  = threadIdx.x;
    const int wave = tid >> 6;
    const int lane = tid & 63;
    const int quad = lane >> 4, l16 = lane & 15;
    const int wrow = wave * 32;
    const size_t mblk = (size_t)blockIdx.x * 128;

    const int r0g = (int)mblk + wrow;
    int gfirst = (r0g < N_NODES) ? batch[r0g] : -2;
    int glast  = (r0g + 31 < N_NODES) ? batch[r0g + 31] : -1;

    bf16x8 a[2][8];

    // ---- layer 1 A-frags from global (K=128) ----
    #pragma unroll
    for (int i = 0; i < 2; ++i)
        #pragma unroll
        for (int s = 0; s < 4; ++s)
            a[i][s] = *(const bf16x8*)(A + (mblk + wrow + i * 16 + l16) * IN_DIM + s * 32 + quad * 8);

    // ---- layer 1: K=128 (KS=4), 8 slabs of 32 cols ----
    for (int j = 0; j < 8; ++j) {
        const __bf16* src = Wp + j * (32 * 128);
        f32x4 acc[2][2] = {};
        #pragma unroll
        for (int s = 0; s < 4; ++s)
            #pragma unroll
            for (int t = 0; t < 2; ++t) {
                bf16x8 b = *(const bf16x8*)(src + ((t * 4 + s) * 64 + lane) * 8);
                acc[0][t] = __builtin_amdgcn_mfma_f32_16x16x32_bf16(a[0][s], b, acc[0][t], 0, 0, 0);
                acc[1][t] = __builtin_amdgcn_mfma_f32_16x16x32_bf16(a[1][s], b, acc[1][t], 0, 0, 0);
            }
        #pragma unroll
        for (int i = 0; i < 2; ++i)
            #pragma unroll
            for (int t = 0; t < 2; ++t)
                #pragma unroll
                for (int rr = 0; rr < 4; ++rr) {
                    int row = wrow + i * 16 + quad * 4 + rr;
                    int col = j * 32 + t * 16 + l16;
                    float v = fmaxf(acc[i][t][rr] + b1[col], 0.f);
                    H[row * 256 + (((col >> 3) + row) & 31) * 8 + (col & 7)] = (__bf16)v;
                }
    }
    __syncthreads();   // LDS write->read visibility (cross-lane within wave)

    // ---- layer 2 A-frags from LDS ----
    #pragma unroll
    for (int i = 0; i < 2; ++i)
        #pragma unroll
        for (int s = 0; s < 8; ++s) {
            int row = wrow + i * 16 + l16;
            a[i][s] = *(const bf16x8*)(H + row * 256 + (((s * 4 + quad) + row) & 31) * 8);
        }
    __syncthreads();   // all reads done before overwrites below

    // ---- layer 2: K=256 (KS=8), 8 slabs of 32 cols ----
    for (int j = 0; j < 8; ++j) {
        const __bf16* src = Wp + WP_L2_BASE + j * (32 * 256);
        f32x4 acc[2][2] = {};
        #pragma unroll
        for (int s = 0; s < 8; ++s)
            #pragma unroll
            for (int t = 0; t < 2; ++t) {
                bf16x8 b = *(const bf16x8*)(src + ((t * 8 + s) * 64 + lane) * 8);
                acc[0][t] = __builtin_amdgcn_mfma_f32_16x16x32_bf16(a[0][s], b, acc[0][t], 0, 0, 0);
                acc[1][t] = __builtin_amdgcn_mfma_f32_16x16x32_bf16(a[1][s], b, acc[1][t], 0, 0, 0);
            }
        #pragma unroll
        for (int i = 0; i < 2; ++i)
            #pragma unroll
            for (int t = 0; t < 2; ++t)
                #pragma unroll
                for (int rr = 0; rr < 4; ++rr) {
                    int row = wrow + i * 16 + quad * 4 + rr;
                    int col = j * 32 + t * 16 + l16;
                    float v = fmaxf(acc[i][t][rr] + b2[col], 0.f);
                    H[row * 256 + (((col >> 3) + row) & 31) * 8 + (col & 7)] = (__bf16)v;
                }
    }
    __syncthreads();

    // ---- layer 3 A-frags from LDS ----
    #pragma unroll
    for (int i = 0; i < 2; ++i)
        #pragma unroll
        for (int s = 0; s < 8; ++s) {
            int row = wrow + i * 16 + l16;
            a[i][s] = *(const bf16x8*)(H + row * 256 + (((s * 4 + quad) + row) & 31) * 8);
        }

    // ---- layer 3: K=256, 4 slabs of 32 cols, pooled atomic output ----
    for (int j = 0; j < 4; ++j) {
        const __bf16* src = Wp + WP_L3_BASE + j * (32 * 256);
        f32x4 acc[2][2] = {};
        #pragma unroll
        for (int s = 0; s < 8; ++s)
            #pragma unroll
            for (int t = 0; t < 2; ++t) {
                bf16x8 b = *(const bf16x8*)(src + ((t * 8 + s) * 64 + lane) * 8);
                acc[0][t] = __builtin_amdgcn_mfma_f32_16x16x32_bf16(a[0][s], b, acc[0][t], 0, 0, 0);
                acc[1][t] = __builtin_amdgcn_mfma_f32_16x16x32_bf16(a[1][s], b, acc[1][t], 0, 0, 0);
            }

        if (gfirst == glast) {
            #pragma unroll
            for (int t = 0; t < 2; ++t) {
                float sum = 0.f;
                #pragma unroll
                for (int i = 0; i < 2; ++i)
                    #pragma unroll
                    for (int rr = 0; rr < 4; ++rr) sum += acc[i][t][rr];
                sum += __shfl_xor(sum, 16, 64);
                sum += __shfl_xor(sum, 32, 64);
                if (quad == 0) {
                    int c = j * 32 + t * 16 + l16;
                    atomicAdd(out + (size_t)gfirst * OUT_DIM + c, sum + 32.f * bo[c]);
                }
            }
        } else {
            #pragma unroll
            for (int i = 0; i < 2; ++i)
                #pragma unroll
                for (int rr = 0; rr < 4; ++rr) {
                    int m = r0g + i * 16 + quad * 4 + rr;
                    if (m < N_NODES) {
                        int g = batch[m];
                        #pragma unroll
                        for (int t = 0; t < 2; ++t) {
                            int c = j * 32 + t * 16 + l16;
                            atomicAdd(out + (size_t)g * OUT_DIM + c, acc[i][t][rr] + bo[c]);
                        }
                    }
                }
        }
    }
}

extern "C" void kernel_launch(void* const* d_in, const int* in_sizes, int n_in,
                              void* d_out, int out_size, void* d_ws, size_t ws_size,
                              hipStream_t stream) {
    const float* x  = (const float*)d_in[0];
    const int*   ei = (const int*)d_in[1];
    const int*   bi = (const int*)d_in[2];
    const float* W1 = (const float*)d_in[3];
    const float* b1 = (const float*)d_in[4];
    const float* W2 = (const float*)d_in[5];
    const float* b2 = (const float*)d_in[6];
    const float* Wo = (const float*)d_in[7];
    const float* bo = (const float*)d_in[8];
    float* out = (float*)d_out;

    __bf16* A  = (__bf16*)d_ws;                        // [M_PAD][128]
    __bf16* xb = A + (size_t)M_PAD * IN_DIM;           // [N_NODES][128]
    __bf16* Wp = xb + (size_t)N_NODES * IN_DIM;        // [131072] packed frag-ordered
    unsigned* pairBuf = (unsigned*)(Wp + WP_TOTAL);    // [NB*BCAP]
    int* nbr      = (int*)(pairBuf + (size_t)NB * BCAP);
    int* offsets  = nbr + (size_t)NB * BCAP;
    int* deg      = offsets + N_NODES;
    int* gcursor  = deg + N_NODES;

    // ---- fused init ----
    init_kernel<<<(R_TOTAL + 255) / 256, 256, 0, stream>>>(
        x, W1, W2, Wo, xb, A + (size_t)N_NODES * IN_DIM, Wp, out, gcursor);

    // ---- CSR build ----
    bucket_v2_kernel<<<BKB, 256, 0, stream>>>(ei, gcursor, pairBuf);
    passB_kernel<<<NB, 256, 0, stream>>>(pairBuf, gcursor, nbr, offsets, deg);

    // ---- aggregate ----
    aggregate_kernel<<<(N_NODES + 3) / 4, 256, 0, stream>>>(xb, offsets, deg, nbr, A);

    // ---- fused MLP + pool ----
    mlp_fused<<<M_PAD / 128, 256, 0, stream>>>(A, Wp, b1, b2, bo, out, bi);
}

// Round 12
// 325.465 us; speedup vs baseline: 1.0493x; 1.0493x over previous
//
#include <hip/hip_runtime.h>

#define N_NODES  100000
#define M_PAD    100096   // 782 * 128 (and 3128 * 32)
#define N_EDGES  1600000
#define N_GRAPHS 512
#define IN_DIM   128
#define HID_DIM  256
#define OUT_DIM  128

#define NB       782      // buckets of 128 nodes
#define BCAP     3072     // mean 2048, +22 sigma headroom
#define CHUNK    2048     // edges per bucket_v2 block
#define BKB      ((N_EDGES + CHUNK - 1) / CHUNK)   // 782

typedef __bf16 bf16x8 __attribute__((ext_vector_type(8)));
typedef __bf16 bf16x4 __attribute__((ext_vector_type(4)));
typedef __bf16 bf16x2 __attribute__((ext_vector_type(2)));
typedef float  f32x4  __attribute__((ext_vector_type(4)));

// ---- packed weight buffer layout (frag-ordered, LINEAR group stream) ----
// 32 groups x 8 frags x 512 elems: L1 groups 0-7, L2 8-23, L3 24-31.
#define WP_L2_BASE 32768
#define WP_L3_BASE 98304
#define WP_TOTAL   131072

// ---------------- fused init ----------------
#define R_X    (N_NODES * IN_DIM / 4)
#define R_APAD ((M_PAD - N_NODES) * IN_DIM / 4)
#define R_WP   WP_TOTAL
#define R_OUT  (N_GRAPHS * OUT_DIM / 4)
#define R_CUR  NB
#define R_TOTAL (R_X + R_APAD + R_WP + R_OUT + R_CUR)

__global__ __launch_bounds__(256) void init_kernel(const float* __restrict__ x,
                                                   const float* __restrict__ W1,
                                                   const float* __restrict__ W2,
                                                   const float* __restrict__ Wo,
                                                   __bf16* __restrict__ xb,
                                                   __bf16* __restrict__ Apad,
                                                   __bf16* __restrict__ Wp,
                                                   float* __restrict__ outbuf,
                                                   int* __restrict__ gcursor) {
    long long i = (long long)blockIdx.x * blockDim.x + threadIdx.x;
    if (i < R_X) {
        float4 v = ((const float4*)x)[i];
        bf16x4 h;
        h.x = (__bf16)v.x; h.y = (__bf16)v.y; h.z = (__bf16)v.z; h.w = (__bf16)v.w;
        ((bf16x4*)xb)[i] = h;
        return;
    }
    i -= R_X;
    if (i < R_APAD) {
        bf16x4 z; z.x = (__bf16)0.f; z.y = (__bf16)0.f; z.z = (__bf16)0.f; z.w = (__bf16)0.f;
        ((bf16x4*)Apad)[i] = z;
        return;
    }
    i -= R_APAD;
    if (i < R_WP) {
        int idx = (int)i;
        const float* src;
        int K, Nn, base;
        if (idx < WP_L2_BASE)      { src = W1; K = 128; Nn = 256; base = 0; }
        else if (idx < WP_L3_BASE) { src = W2; K = 256; Nn = 256; base = WP_L2_BASE; }
        else                       { src = Wo; K = 256; Nn = 128; base = WP_L3_BASE; }
        int r0 = idx - base;
        int slabElems = 32 * K;          // power of two
        int j = r0 / slabElems;
        int r = r0 % slabElems;
        int KS = K / 32;
        int p = r >> 9;
        int lane = (r >> 3) & 63;
        int e = r & 7;
        int s = p % KS, t = p / KS;
        int quad = lane >> 4, l16 = lane & 15;
        int n = j * 32 + t * 16 + l16;
        int k = s * 32 + quad * 8 + e;
        Wp[idx] = (__bf16)src[(size_t)k * Nn + n];
        return;
    }
    i -= R_WP;
    if (i < R_OUT) {
        ((float4*)outbuf)[i] = make_float4(0.f, 0.f, 0.f, 0.f);
        return;
    }
    i -= R_OUT;
    if (i < R_CUR) gcursor[i] = 0;
}

// ---------------- bucket_v2: LDS-staged edge binning ----------------
__global__ __launch_bounds__(256) void bucket_v2_kernel(const int* __restrict__ ei,
                                                        int* __restrict__ gcursor,
                                                        unsigned* __restrict__ pairBuf) {
    __shared__ int lcnt[NB];
    __shared__ int lbase[NB];
    const int tid = threadIdx.x;
    const int e0 = blockIdx.x * CHUNK;

    for (int b = tid; b < NB; b += 256) lcnt[b] = 0;
    __syncthreads();

    for (int i = tid; i < CHUNK; i += 256) {
        int e = e0 + i;
        if (e < N_EDGES) atomicAdd(&lcnt[ei[N_EDGES + e] >> 7], 1);
    }
    __syncthreads();

    for (int b = tid; b < NB; b += 256) {
        int c = lcnt[b];
        lbase[b] = c ? atomicAdd(&gcursor[b], c) : 0;
        lcnt[b] = 0;
    }
    __syncthreads();

    for (int i = tid; i < CHUNK; i += 256) {
        int e = e0 + i;
        if (e < N_EDGES) {
            int s = ei[e];
            int d = ei[N_EDGES + e];
            int b = d >> 7;
            int pos = lbase[b] + atomicAdd(&lcnt[b], 1);
            if (pos < BCAP)
                pairBuf[(size_t)b * BCAP + pos] = (unsigned)s | ((unsigned)(d & 127) << 17);
        }
    }
}

// ---------------- passB: per-bucket CSR build (bucket-strided) ----------------
__global__ __launch_bounds__(256) void passB_kernel(const unsigned* __restrict__ pairBuf,
                                                    const int* __restrict__ gcursor,
                                                    int* __restrict__ nbr,
                                                    int* __restrict__ offsets,
                                                    int* __restrict__ deg) {
    __shared__ int lcnt[128];
    __shared__ int loffs[128];
    __shared__ int lcur[128];
    const int b = blockIdx.x;
    const int tid = threadIdx.x;
    const int node0 = b << 7;
    const int cnt = min(gcursor[b], BCAP);
    const int base = b * BCAP;
    const unsigned* pb = pairBuf + (size_t)b * BCAP;

    if (tid < 128) { lcnt[tid] = 0; lcur[tid] = 0; }
    __syncthreads();

    for (int i = tid; i < cnt; i += 256)
        atomicAdd(&lcnt[pb[i] >> 17], 1);
    __syncthreads();

    if (tid < 128) loffs[tid] = lcnt[tid];
    __syncthreads();
    for (int st = 1; st < 128; st <<= 1) {
        int add = (tid < 128 && tid >= st) ? loffs[tid - st] : 0;
        __syncthreads();
        if (tid < 128) loffs[tid] += add;
        __syncthreads();
    }
    int excl = 0;
    if (tid < 128) {
        excl = loffs[tid] - lcnt[tid];
        int node = node0 + tid;
        if (node < N_NODES) {
            deg[node] = lcnt[tid];
            offsets[node] = base + excl;
        }
    }
    __syncthreads();
    if (tid < 128) loffs[tid] = excl;
    __syncthreads();

    for (int i = tid; i < cnt; i += 256) {
        unsigned u = pb[i];
        int dl = u >> 17;
        int slot = atomicAdd(&lcur[dl], 1);
        nbr[base + loffs[dl] + slot] = (int)(u & 0x1FFFF);
    }
}

// ---------------- gather aggregate (at memory floor) ----------------
__global__ __launch_bounds__(256) void aggregate_kernel(const __bf16* __restrict__ xb,
                                                        const int* __restrict__ offsets,
                                                        const int* __restrict__ deg,
                                                        const int* __restrict__ nbr,
                                                        __bf16* __restrict__ A) {
    int v = blockIdx.x * 4 + (threadIdx.x >> 6);
    v = __builtin_amdgcn_readfirstlane(v);
    int lane = threadIdx.x & 63;
    if (v >= N_NODES) return;
    int off = offsets[v];
    int len = deg[v];
    const int c0 = lane * 2;
    bf16x2 self = *(const bf16x2*)(xb + (size_t)v * IN_DIM + c0);
    float ax = (float)self.x, ay = (float)self.y;

    int addr = off + lane;
    if (addr > NB * BCAP - 1) addr = NB * BCAP - 1;
    int myidx = nbr[addr];

    int lim = len < 64 ? len : 64;
    int j = 0;
    for (; j + 8 <= lim; j += 8) {
        int s0 = __shfl(myidx, j + 0, 64);
        int s1 = __shfl(myidx, j + 1, 64);
        int s2 = __shfl(myidx, j + 2, 64);
        int s3 = __shfl(myidx, j + 3, 64);
        int s4 = __shfl(myidx, j + 4, 64);
        int s5 = __shfl(myidx, j + 5, 64);
        int s6 = __shfl(myidx, j + 6, 64);
        int s7 = __shfl(myidx, j + 7, 64);
        bf16x2 v0 = *(const bf16x2*)(xb + (size_t)s0 * IN_DIM + c0);
        bf16x2 v1 = *(const bf16x2*)(xb + (size_t)s1 * IN_DIM + c0);
        bf16x2 v2 = *(const bf16x2*)(xb + (size_t)s2 * IN_DIM + c0);
        bf16x2 v3 = *(const bf16x2*)(xb + (size_t)s3 * IN_DIM + c0);
        bf16x2 v4 = *(const bf16x2*)(xb + (size_t)s4 * IN_DIM + c0);
        bf16x2 v5 = *(const bf16x2*)(xb + (size_t)s5 * IN_DIM + c0);
        bf16x2 v6 = *(const bf16x2*)(xb + (size_t)s6 * IN_DIM + c0);
        bf16x2 v7 = *(const bf16x2*)(xb + (size_t)s7 * IN_DIM + c0);
        ax += (float)v0.x + (float)v1.x + (float)v2.x + (float)v3.x
            + (float)v4.x + (float)v5.x + (float)v6.x + (float)v7.x;
        ay += (float)v0.y + (float)v1.y + (float)v2.y + (float)v3.y
            + (float)v4.y + (float)v5.y + (float)v6.y + (float)v7.y;
    }
    for (; j < lim; ++j) {
        int s = __shfl(myidx, j, 64);
        bf16x2 vv = *(const bf16x2*)(xb + (size_t)s * IN_DIM + c0);
        ax += (float)vv.x;
        ay += (float)vv.y;
    }
    for (; j < len; ++j) {
        int s = nbr[off + j];
        bf16x2 vv = *(const bf16x2*)(xb + (size_t)s * IN_DIM + c0);
        ax += (float)vv.x;
        ay += (float)vv.y;
    }
    bf16x2 h;
    h.x = (__bf16)ax;
    h.y = (__bf16)ay;
    *(bf16x2*)(A + (size_t)v * IN_DIM + c0) = h;
}

// ---------------- fused 3-layer MLP + pool, 1-wave blocks + reg dbuf B-stream ----------------
// Block = 64 thr (1 wave), owns 32 rows; H strip 16 KB -> 10 blocks/CU.
// Wp is a LINEAR stream of 32 groups x 8 frags (4 KB); prefetch group g+1 into
// the alternate register buffer while MFMAing group g (vmcnt never drains).
__device__ __forceinline__ void load_group(const __bf16* __restrict__ Wp, int g, int lane,
                                           bf16x8* __restrict__ dst) {
    const __bf16* p = Wp + (size_t)g * 4096;
    #pragma unroll
    for (int e = 0; e < 8; ++e)
        dst[e] = *(const bf16x8*)(p + (e * 64 + lane) * 8);
}

__global__ __launch_bounds__(64) void mlp_fused(const __bf16* __restrict__ A,
                                                const __bf16* __restrict__ Wp,
                                                const float* __restrict__ b1,
                                                const float* __restrict__ b2,
                                                const float* __restrict__ bo,
                                                float* __restrict__ out,
                                                const int* __restrict__ batch) {
    __shared__ __bf16 H[32 * 256];   // 16 KB

    const int lane = threadIdx.x;
    const int quad = lane >> 4, l16 = lane & 15;
    const size_t mblk = (size_t)blockIdx.x * 32;
    const int r0g = (int)mblk;
    int gfirst = (r0g < N_NODES) ? batch[r0g] : -2;
    int glast  = (r0g + 31 < N_NODES) ? batch[r0g + 31] : -1;

    bf16x8 a[2][8];
    bf16x8 buf[2][8];

    // group 0 prefetch + layer-1 A-frags + layer-1 bias preload
    load_group(Wp, 0, lane, buf[0]);
    #pragma unroll
    for (int i = 0; i < 2; ++i)
        #pragma unroll
        for (int s = 0; s < 4; ++s)
            a[i][s] = *(const bf16x8*)(A + (mblk + i * 16 + l16) * IN_DIM + s * 32 + quad * 8);
    float bias[16];
    #pragma unroll
    for (int j = 0; j < 8; ++j) {
        bias[j * 2 + 0] = b1[j * 32 + l16];
        bias[j * 2 + 1] = b1[j * 32 + 16 + l16];
    }

    // ---- layer 1: groups 0..7 (1 group = 1 slab of 32 cols, KS=4) ----
    #pragma unroll
    for (int j = 0; j < 8; ++j) {
        const int cur = j & 1;
        load_group(Wp, j + 1, lane, buf[cur ^ 1]);   // prefetch next
        f32x4 acc[2][2] = {};
        #pragma unroll
        for (int p = 0; p < 8; ++p) {
            const int t = p >> 2, s = p & 3;
            acc[0][t] = __builtin_amdgcn_mfma_f32_16x16x32_bf16(a[0][s], buf[cur][p], acc[0][t], 0, 0, 0);
            acc[1][t] = __builtin_amdgcn_mfma_f32_16x16x32_bf16(a[1][s], buf[cur][p], acc[1][t], 0, 0, 0);
        }
        #pragma unroll
        for (int i = 0; i < 2; ++i)
            #pragma unroll
            for (int t = 0; t < 2; ++t)
                #pragma unroll
                for (int rr = 0; rr < 4; ++rr) {
                    int row = i * 16 + quad * 4 + rr;
                    int col = j * 32 + t * 16 + l16;
                    float v = fmaxf(acc[i][t][rr] + bias[j * 2 + t], 0.f);
                    H[row * 256 + (((col >> 3) + row) & 31) * 8 + (col & 7)] = (__bf16)v;
                }
    }
    __syncthreads();

    // ---- layer 2 A-frags from LDS + bias preload ----
    #pragma unroll
    for (int i = 0; i < 2; ++i)
        #pragma unroll
        for (int s = 0; s < 8; ++s) {
            int row = i * 16 + l16;
            a[i][s] = *(const bf16x8*)(H + row * 256 + (((s * 4 + quad) + row) & 31) * 8);
        }
    #pragma unroll
    for (int j = 0; j < 8; ++j) {
        bias[j * 2 + 0] = b2[j * 32 + l16];
        bias[j * 2 + 1] = b2[j * 32 + 16 + l16];
    }
    __syncthreads();

    // ---- layer 2: groups 8..23 (slab j -> groups 8+2j (t=0), 9+2j (t=1)) ----
    #pragma unroll
    for (int j = 0; j < 8; ++j) {
        f32x4 acc[2][2] = {};
        #pragma unroll
        for (int g2 = 0; g2 < 2; ++g2) {
            const int cur = g2;                       // group 8+2j+g2 has parity g2
            load_group(Wp, 8 + 2 * j + g2 + 1, lane, buf[cur ^ 1]);
            #pragma unroll
            for (int p = 0; p < 8; ++p) {
                acc[0][g2] = __builtin_amdgcn_mfma_f32_16x16x32_bf16(a[0][p], buf[cur][p], acc[0][g2], 0, 0, 0);
                acc[1][g2] = __builtin_amdgcn_mfma_f32_16x16x32_bf16(a[1][p], buf[cur][p], acc[1][g2], 0, 0, 0);
            }
        }
        #pragma unroll
        for (int i = 0; i < 2; ++i)
            #pragma unroll
            for (int t = 0; t < 2; ++t)
                #pragma unroll
                for (int rr = 0; rr < 4; ++rr) {
                    int row = i * 16 + quad * 4 + rr;
                    int col = j * 32 + t * 16 + l16;
                    float v = fmaxf(acc[i][t][rr] + bias[j * 2 + t], 0.f);
                    H[row * 256 + (((col >> 3) + row) & 31) * 8 + (col & 7)] = (__bf16)v;
                }
    }
    __syncthreads();

    // ---- layer 3 A-frags from LDS + bias preload ----
    #pragma unroll
    for (int i = 0; i < 2; ++i)
        #pragma unroll
        for (int s = 0; s < 8; ++s) {
            int row = i * 16 + l16;
            a[i][s] = *(const bf16x8*)(H + row * 256 + (((s * 4 + quad) + row) & 31) * 8);
        }
    #pragma unroll
    for (int j = 0; j < 4; ++j) {
        bias[j * 2 + 0] = bo[j * 32 + l16];
        bias[j * 2 + 1] = bo[j * 32 + 16 + l16];
    }

    // ---- layer 3: groups 24..31 (4 slabs), pooled atomic output ----
    #pragma unroll
    for (int j = 0; j < 4; ++j) {
        f32x4 acc[2][2] = {};
        #pragma unroll
        for (int g2 = 0; g2 < 2; ++g2) {
            const int cur = g2;
            load_group(Wp, 24 + 2 * j + g2 + 1, lane, buf[cur ^ 1]);  // last reads past Wp into pairBuf (harmless)
            #pragma unroll
            for (int p = 0; p < 8; ++p) {
                acc[0][g2] = __builtin_amdgcn_mfma_f32_16x16x32_bf16(a[0][p], buf[cur][p], acc[0][g2], 0, 0, 0);
                acc[1][g2] = __builtin_amdgcn_mfma_f32_16x16x32_bf16(a[1][p], buf[cur][p], acc[1][g2], 0, 0, 0);
            }
        }

        if (gfirst == glast) {
            #pragma unroll
            for (int t = 0; t < 2; ++t) {
                float sum = 0.f;
                #pragma unroll
                for (int i = 0; i < 2; ++i)
                    #pragma unroll
                    for (int rr = 0; rr < 4; ++rr) sum += acc[i][t][rr];
                sum += __shfl_xor(sum, 16, 64);
                sum += __shfl_xor(sum, 32, 64);
                if (quad == 0) {
                    int c = j * 32 + t * 16 + l16;
                    atomicAdd(out + (size_t)gfirst * OUT_DIM + c, sum + 32.f * bias[j * 2 + t]);
                }
            }
        } else {
            #pragma unroll
            for (int i = 0; i < 2; ++i)
                #pragma unroll
                for (int rr = 0; rr < 4; ++rr) {
                    int m = r0g + i * 16 + quad * 4 + rr;
                    if (m < N_NODES) {
                        int g = batch[m];
                        #pragma unroll
                        for (int t = 0; t < 2; ++t) {
                            int c = j * 32 + t * 16 + l16;
                            atomicAdd(out + (size_t)g * OUT_DIM + c, acc[i][t][rr] + bias[j * 2 + t]);
                        }
                    }
                }
        }
    }
}

extern "C" void kernel_launch(void* const* d_in, const int* in_sizes, int n_in,
                              void* d_out, int out_size, void* d_ws, size_t ws_size,
                              hipStream_t stream) {
    const float* x  = (const float*)d_in[0];
    const int*   ei = (const int*)d_in[1];
    const int*   bi = (const int*)d_in[2];
    const float* W1 = (const float*)d_in[3];
    const float* b1 = (const float*)d_in[4];
    const float* W2 = (const float*)d_in[5];
    const float* b2 = (const float*)d_in[6];
    const float* Wo = (const float*)d_in[7];
    const float* bo = (const float*)d_in[8];
    float* out = (float*)d_out;

    __bf16* A  = (__bf16*)d_ws;                        // [M_PAD][128]
    __bf16* xb = A + (size_t)M_PAD * IN_DIM;           // [N_NODES][128]
    __bf16* Wp = xb + (size_t)N_NODES * IN_DIM;        // [131072] packed frag-ordered
    unsigned* pairBuf = (unsigned*)(Wp + WP_TOTAL);    // [NB*BCAP]
    int* nbr      = (int*)(pairBuf + (size_t)NB * BCAP);
    int* offsets  = nbr + (size_t)NB * BCAP;
    int* deg      = offsets + N_NODES;
    int* gcursor  = deg + N_NODES;

    // ---- fused init ----
    init_kernel<<<(R_TOTAL + 255) / 256, 256, 0, stream>>>(
        x, W1, W2, Wo, xb, A + (size_t)N_NODES * IN_DIM, Wp, out, gcursor);

    // ---- CSR build ----
    bucket_v2_kernel<<<BKB, 256, 0, stream>>>(ei, gcursor, pairBuf);
    passB_kernel<<<NB, 256, 0, stream>>>(pairBuf, gcursor, nbr, offsets, deg);

    // ---- aggregate ----
    aggregate_kernel<<<(N_NODES + 3) / 4, 256, 0, stream>>>(xb, offsets, deg, nbr, A);

    // ---- fused MLP + pool (1-wave blocks) ----
    mlp_fused<<<M_PAD / 32, 64, 0, stream>>>(A, Wp, b1, b2, bo, out, bi);
}